// Round 5
// baseline (265.366 us; speedup 1.0000x reference)
//
#include <hip/hip_runtime.h>

#define N_NODES 100000
#define N_EDGES 3200000
#define N_GRAPHS 512
#define IN_CH 50
#define HID 256
#define NB 391          // buckets of 256 nodes
#define NBLK 196        // edge blocks
#define EPB 16384       // edges per block

typedef unsigned short ushort_t;
using s16x8 = __attribute__((ext_vector_type(8))) short;
using us8   = __attribute__((ext_vector_type(8))) unsigned short;
using us4   = __attribute__((ext_vector_type(4))) unsigned short;
using f32x4 = __attribute__((ext_vector_type(4))) float;

__device__ __forceinline__ float bf2f(ushort_t u) {
    return __uint_as_float(((unsigned int)u) << 16);
}
__device__ __forceinline__ ushort_t f2bf(float f) {
    unsigned int x = __float_as_uint(f);
    unsigned int r = x + 0x7fffu + ((x >> 16) & 1u);
    return (ushort_t)(r >> 16);
}
__device__ __forceinline__ int clampi(int v, int hi) {
    return v < 0 ? 0 : (v >= hi ? hi - 1 : v);
}

// fp8 e4m3fn encode (RNE, saturate to 448) / decode
__device__ __forceinline__ unsigned char f2e4(float f) {
    unsigned char s = (unsigned char)((__float_as_uint(f) >> 31) << 7);
    float a = fabsf(f);
    if (a >= 0.015625f) {
        if (a > 448.f) a = 448.f;
        unsigned int u = __float_as_uint(a);
        u += 0x7FFFFu + ((u >> 20) & 1u);     // RNE into 3-bit mantissa
        int e8 = (int)(u >> 23) - 127 + 7;
        unsigned int m8 = (u >> 20) & 7u;
        if (e8 > 15) { e8 = 15; m8 = 6; }
        return s | (unsigned char)((e8 << 3) | m8);
    } else {
        int m = (int)rintf(a * 512.f);
        if (m > 7) return s | 0x08;
        return s | (unsigned char)m;
    }
}
// branchless e4m3 -> f32: exact for normals AND denormals (bit-place + 2^120 scale)
__device__ __forceinline__ float e42f(unsigned int c) {
    unsigned int w = ((c & 0x80u) << 24) | ((c & 0x7fu) << 20);
    return __uint_as_float(w) * 0x1p120f;
}

// fp8 byte -> f32: hardware convert when available (gfx950 OCP e4m3fn).
// NOTE: byte-select must be a LITERAL constant (builtin checks before unroll).
#if __has_builtin(__builtin_amdgcn_cvt_f32_fp8)
#define CV8(u, k) __builtin_amdgcn_cvt_f32_fp8((int)(u), (k))
#else
#define CV8(u, k) e42f(((u) >> (8 * (k))) & 0xffu)
#endif

// accumulate 4 fp8 bytes of word w (masked by m) into a[base..base+3]
#define ACC4(w, m, base)                               \
    do {                                               \
        a[(base) + 0] = fmaf(CV8((w), 0), (m), a[(base) + 0]); \
        a[(base) + 1] = fmaf(CV8((w), 1), (m), a[(base) + 1]); \
        a[(base) + 2] = fmaf(CV8((w), 2), (m), a[(base) + 2]); \
        a[(base) + 3] = fmaf(CV8((w), 3), (m), a[(base) + 3]); \
    } while (0)

// ---- workspace layout (bytes), total 32,629,124 (proven ws_size >= 39,272,064) ----
constexpr size_t OFF_GACC   = 0;          // 512*2*4 = 4096
constexpr size_t OFF_BASE   = 6144;       // (NB+1)*4 = 1568
constexpr size_t ZBYTES     = 8192;       // zeroed prefix
constexpr size_t OFF_COUNTS = 8192;       // u16 [NBLK][NB] = 153272 -> pad 161536
constexpr size_t OFF_SD     = 161536;     // packed (start<<10|deg) u32 [N] = 400000
constexpr size_t OFF_SRC    = 561536;     // int [E] = 12.8MB; xb bf16 [N,64] overlays after gather
constexpr size_t OFF_X8     = 13361536;   // fp8 [N,64] = 6.4MB
constexpr size_t OFF_EP     = 19761536;   // epairs int [E] = 12.8MB; agg bf16 [N,64] overlays
constexpr size_t OFF_WT     = 32561536;   // bf16 [256][128] = 65536 -> end 32,627,072
constexpr size_t OFF_BND    = 32627072;   // int [N_GRAPHS+1] = 2052 (no zero-init needed)

// P1: per-(block,bucket) edge counts via LDS histogram
__global__ __launch_bounds__(256) void k_count(const int* __restrict__ ei,
                                               ushort_t* __restrict__ counts) {
    __shared__ int h[NB];
    int blk = blockIdx.x, t = threadIdx.x;
    for (int i = t; i < NB; i += 256) h[i] = 0;
    __syncthreads();
    int e0 = blk * EPB;
    for (int i = 0; i < EPB; i += 256) {
        int e = e0 + i + t;
        if (e < N_EDGES) {
            int d = clampi(ei[N_EDGES + e], N_NODES);
            atomicAdd(&h[d >> 8], 1);
        }
    }
    __syncthreads();
    for (int i = t; i < NB; i += 256) counts[blk * NB + i] = (ushort_t)h[i];
}

// P2a: per-bucket column scan
__global__ __launch_bounds__(256) void k_scan_col(ushort_t* __restrict__ counts,
                                                  int* __restrict__ base) {
    __shared__ int a[256];
    __shared__ int orig[256];
    int b = blockIdx.x, t = threadIdx.x;
    int v = (t < NBLK) ? (int)counts[t * NB + b] : 0;
    orig[t] = v; a[t] = v;
    __syncthreads();
    for (int off = 1; off < 256; off <<= 1) {
        int u = (t >= off) ? a[t - off] : 0;
        __syncthreads();
        a[t] += u;
        __syncthreads();
    }
    if (t < NBLK) counts[t * NB + b] = (ushort_t)(a[t] - orig[t]);
    if (t == 255) base[b] = a[255];
}

// P2b: exclusive scan over bucket totals
__global__ __launch_bounds__(512) void k_scan_bucket(int* __restrict__ base) {
    __shared__ int a[512];
    __shared__ int orig[512];
    int t = threadIdx.x;
    int v = (t < NB) ? base[t] : 0;
    orig[t] = v; a[t] = v;
    __syncthreads();
    for (int off = 1; off < 512; off <<= 1) {
        int u = (t >= off) ? a[t - off] : 0;
        __syncthreads();
        a[t] += u;
        __syncthreads();
    }
    if (t < NB) base[t] = a[t] - orig[t];
    if (t == NB - 1) base[NB] = a[t];
}

// P3: scatter edges into bucket-contiguous runs; pack (src<<8)|dst_local
__global__ __launch_bounds__(256) void k_scatter(const int* __restrict__ ei,
                                                 const ushort_t* __restrict__ counts,
                                                 const int* __restrict__ base,
                                                 int* __restrict__ ep) {
    __shared__ int rnk[NB];
    __shared__ int ob[NB];
    int blk = blockIdx.x, t = threadIdx.x;
    for (int i = t; i < NB; i += 256) {
        rnk[i] = 0;
        ob[i] = base[i] + (int)counts[blk * NB + i];
    }
    __syncthreads();
    int e0 = blk * EPB;
    for (int i = 0; i < EPB; i += 256) {
        int e = e0 + i + t;
        if (e < N_EDGES) {
            int s = clampi(ei[e], N_NODES);
            int d = clampi(ei[N_EDGES + e], N_NODES);
            int b = d >> 8;
            int r = atomicAdd(&rnk[b], 1);
            ep[ob[b] + r] = (s << 8) | (d & 255);
        }
    }
}

// P4: per-bucket fine CSR; emit packed start|deg
__global__ __launch_bounds__(256) void k_csr(const int* __restrict__ ep,
                                             const int* __restrict__ base,
                                             int* __restrict__ srcs,
                                             unsigned int* __restrict__ sd) {
    __shared__ int ldeg[256];
    __shared__ int a[256];
    __shared__ int lcur[256];
    int b = blockIdx.x, t = threadIdx.x;
    int e0 = base[b], e1 = base[b + 1];
    ldeg[t] = 0;
    __syncthreads();
    for (int e = e0 + t; e < e1; e += 256) atomicAdd(&ldeg[ep[e] & 255], 1);
    __syncthreads();
    a[t] = ldeg[t];
    __syncthreads();
    for (int off = 1; off < 256; off <<= 1) {
        int u = (t >= off) ? a[t - off] : 0;
        __syncthreads();
        a[t] += u;
        __syncthreads();
    }
    int excl = a[t] - ldeg[t];
    lcur[t] = excl;
    __syncthreads();
    int n = (b << 8) + t;
    if (n < N_NODES) {
        int dgc = ldeg[t] < 1023 ? ldeg[t] : 1023;
        sd[n] = ((unsigned int)(e0 + excl) << 10) | (unsigned int)dgc;
    }
    for (int e = e0 + t; e < e1; e += 256) {
        int p = ep[e];
        int dl = p & 255;
        int r = atomicAdd(&lcur[dl], 1);
        srcs[e0 + r] = p >> 8;
    }
}

// K4: combined transposed bf16 weight WT[j][k]
__global__ void k_buildW(const float* __restrict__ Wl, const float* __restrict__ Wr,
                         ushort_t* __restrict__ WT) {
    int idx = blockIdx.x * blockDim.x + threadIdx.x;
    int j = idx >> 7;
    int k = idx & 127;
    ushort_t val = 0;
    if (k < IN_CH) val = f2bf(Wl[j * IN_CH + k]);
    else if (k >= 64 && k < 64 + IN_CH) val = f2bf(Wr[j * IN_CH + (k - 64)]);
    WT[idx] = val;
}

// K4b: x fp32 [N,50] -> x8 fp8 [N,64] (cols 50..63 = 0)
__global__ void k_conv8(const float* __restrict__ x, unsigned char* __restrict__ x8) {
    int t = blockIdx.x * blockDim.x + threadIdx.x;
    if (t < N_NODES * 64) {
        int n = t >> 6, c = t & 63;
        x8[t] = (c < IN_CH) ? f2e4(x[n * IN_CH + c]) : (unsigned char)0;
    }
}

// K4c: graph boundaries from SORTED batch -> bnd[g] = first node with batch >= g.
__global__ void k_bounds(const int* __restrict__ batch, int* __restrict__ bnd) {
    int n = blockIdx.x * blockDim.x + threadIdx.x;
    if (n >= N_NODES) return;
    int b = clampi(batch[n], N_GRAPHS);
    if (n == 0) {
        for (int g = 0; g <= b; ++g) bnd[g] = 0;
    } else {
        int a = clampi(batch[n - 1], N_GRAPHS);
        for (int g = a + 1; g <= b; ++g) bnd[g] = n;
    }
    if (n == N_NODES - 1) {
        for (int g = b + 1; g <= N_GRAPHS; ++g) bnd[g] = N_NODES;
    }
}

// K4d: x fp32 [N,50] -> xb bf16 [N,64] (cols 50..63 = 0); us4-vectorized stores.
// Runs AFTER k_gather8 (overlays dead srcs region).
__global__ __launch_bounds__(256) void k_convb(const float* __restrict__ x,
                                               ushort_t* __restrict__ xb) {
    int t = blockIdx.x * blockDim.x + threadIdx.x;
    if (t >= N_NODES * 16) return;
    int n = t >> 4, c4 = (t & 15) << 2;
    us4 o;
#pragma unroll
    for (int j = 0; j < 4; j++) {
        int c = c4 + j;
        o[j] = (c < IN_CH) ? f2bf(x[n * IN_CH + c]) : (ushort_t)0;
    }
    *(us4*)(xb + (size_t)n * 64 + c4) = o;
}

// K5 v4: wave-per-node gather mean from fp8 x8 (no atomics).
__global__ __launch_bounds__(256) void k_gather8(const unsigned char* __restrict__ x8,
                          const unsigned int* __restrict__ sd,
                          const int* __restrict__ srcs, ushort_t* __restrict__ agg) {
    int gid = (blockIdx.x * blockDim.x + threadIdx.x) >> 6;
    int lane = threadIdx.x & 63;
    if (gid >= N_NODES) return;
    int r8 = lane >> 3;          // row within group of 8
    int c8 = lane & 7;           // byte-octet within 64B row
    unsigned int v = sd[gid];
    int dg = (int)(v & 1023u);
    int st = (int)(v >> 10);

    float a[8];
#pragma unroll
    for (int b = 0; b < 8; ++b) a[b] = 0.f;

    const int nit = (dg + 31) >> 5;
    const int cb = c8 << 3;      // byte offset within row
    for (int it = 0; it < nit; ++it) {
        int i0 = (it << 5) + r8;
        int i1 = i0 + 8, i2 = i0 + 16, i3 = i0 + 24;
        int s0 = srcs[st + (i0 < dg ? i0 : 0)];
        int s1 = srcs[st + (i1 < dg ? i1 : 0)];
        int s2 = srcs[st + (i2 < dg ? i2 : 0)];
        int s3 = srcs[st + (i3 < dg ? i3 : 0)];
        uint2 w0 = *(const uint2*)(x8 + (size_t)s0 * 64 + cb);
        uint2 w1 = *(const uint2*)(x8 + (size_t)s1 * 64 + cb);
        uint2 w2 = *(const uint2*)(x8 + (size_t)s2 * 64 + cb);
        uint2 w3 = *(const uint2*)(x8 + (size_t)s3 * 64 + cb);
        float m0 = i0 < dg ? 1.f : 0.f;
        float m1 = i1 < dg ? 1.f : 0.f;
        float m2 = i2 < dg ? 1.f : 0.f;
        float m3 = i3 < dg ? 1.f : 0.f;
        ACC4(w0.x, m0, 0); ACC4(w0.y, m0, 4);
        ACC4(w1.x, m1, 0); ACC4(w1.y, m1, 4);
        ACC4(w2.x, m2, 0); ACC4(w2.y, m2, 4);
        ACC4(w3.x, m3, 0); ACC4(w3.y, m3, 4);
    }

#pragma unroll
    for (int b = 0; b < 8; ++b) {
        a[b] += __shfl_xor(a[b], 8);
        a[b] += __shfl_xor(a[b], 16);
        a[b] += __shfl_xor(a[b], 32);
    }
    float inv = 1.0f / (float)(dg > 1 ? dg : 1);
    if (r8 == 0) {
        us8 o;
#pragma unroll
        for (int b = 0; b < 8; ++b) o[b] = f2bf(a[b] * inv);
        *(us8*)(agg + (size_t)gid * 64 + cb) = o;
    }
}

// K6 v2b: fused MFMA GEMM [N,128]x[128,256] + bias + leaky_relu + W_c proj + graph-sum.
// B (constant WT) in registers per wave; single A-stage (agg || xb).
// FIX vs v2: each staging thread copies its FULL 32-short chunk (4x us8, not 2x).
__global__ __launch_bounds__(256) void k_gemm(const ushort_t* __restrict__ agg,
                                              const ushort_t* __restrict__ xb,
                                              const ushort_t* __restrict__ WT,
                                              const float* __restrict__ bl,
                                              const float* __restrict__ Wc,
                                              const int* __restrict__ batch,
                                              float* __restrict__ gacc) {
    __shared__ ushort_t Alds[64 * 136];   // row stride 136 shorts (pad 8)
    __shared__ float ypart[4][64][2];
    __shared__ float gred[64][2];

    const int t = threadIdx.x;
    const int w = t >> 6;
    const int lane = t & 63;
    const int quad = lane >> 4;
    const int r16 = lane & 15;
    const int row0 = blockIdx.x * 64;

    if (t < 128) gred[t >> 1][t & 1] = 0.f;

    // B-fragments: wave w covers cols w*64 + 16*ni + r16; k = s*32 + quad*8 .. +7
    s16x8 bfr[4][4];
#pragma unroll
    for (int s = 0; s < 4; ++s)
#pragma unroll
        for (int ni = 0; ni < 4; ++ni)
            bfr[s][ni] = *(const s16x8*)(WT + (size_t)(w * 64 + 16 * ni + r16) * 128
                                            + s * 32 + (quad << 3));

    // A-stage: thread t covers row t>>2, 32-short chunk q4 = t&3
    // cols 0..63 = agg (q4 0,1), cols 64..127 = xb (q4 2,3); 32 shorts = 4x us8
    {
        int row = t >> 2;
        int q4 = t & 3;
        int gr = row0 + row;
        us8* dst = (us8*)&Alds[row * 136 + q4 * 32];
        if (gr < N_NODES) {
            const us8* src = (q4 < 2)
                ? (const us8*)(agg + (size_t)gr * 64 + (q4 & 1) * 32)
                : (const us8*)(xb + (size_t)gr * 64 + (q4 & 1) * 32);
            dst[0] = src[0];
            dst[1] = src[1];
            dst[2] = src[2];
            dst[3] = src[3];
        } else {
            us8 z = {0, 0, 0, 0, 0, 0, 0, 0};
            dst[0] = z; dst[1] = z; dst[2] = z; dst[3] = z;
        }
    }
    __syncthreads();

    f32x4 acc[4][4] = {};
#pragma unroll
    for (int s = 0; s < 4; ++s) {
        s16x8 af[4];
#pragma unroll
        for (int mi = 0; mi < 4; mi++)
            af[mi] = *(const s16x8*)&Alds[(16 * mi + r16) * 136 + s * 32 + (quad << 3)];
#pragma unroll
        for (int mi = 0; mi < 4; mi++)
#pragma unroll
            for (int ni = 0; ni < 4; ni++)
                acc[mi][ni] = __builtin_amdgcn_mfma_f32_16x16x32_bf16(
                    af[mi], bfr[s][ni], acc[mi][ni], 0, 0, 0);
    }

    float blv[4], w0v[4], w1v[4];
#pragma unroll
    for (int ni = 0; ni < 4; ni++) {
        int col = w * 64 + 16 * ni + r16;
        blv[ni] = bl[col];
        w0v[ni] = Wc[col];
        w1v[ni] = Wc[HID + col];
    }
#pragma unroll
    for (int mi = 0; mi < 4; mi++) {
#pragma unroll
        for (int r = 0; r < 4; r++) {
            float p0 = 0.f, p1 = 0.f;
#pragma unroll
            for (int ni = 0; ni < 4; ni++) {
                float h = acc[mi][ni][r] + blv[ni];
                h = (h > 0.f) ? h : 0.01f * h;
                p0 = fmaf(h, w0v[ni], p0);
                p1 = fmaf(h, w1v[ni], p1);
            }
#pragma unroll
            for (int off = 1; off < 16; off <<= 1) {
                p0 += __shfl_xor(p0, off, 16);
                p1 += __shfl_xor(p1, off, 16);
            }
            if (r16 == 0) {
                int rl = 16 * mi + (quad << 2) + r;
                ypart[w][rl][0] = p0;
                ypart[w][rl][1] = p1;
            }
        }
    }
    __syncthreads();

    // per-graph LDS reduce, then few global atomics
    int last = row0 + 63;
    if (last >= N_NODES) last = N_NODES - 1;
    int gmin = clampi(batch[row0], N_GRAPHS);
    int gmax = clampi(batch[last], N_GRAPHS);
    int gspan = gmax - gmin + 1;

    if (t < 128) {
        int rl = t >> 1, cc = t & 1;
        int node = row0 + rl;
        if (node < N_NODES) {
            float s = ypart[0][rl][cc] + ypart[1][rl][cc] + ypart[2][rl][cc] + ypart[3][rl][cc];
            int g = clampi(batch[node], N_GRAPHS);
            if (gspan <= 64) atomicAdd(&gred[g - gmin][cc], s);
            else atomicAdd(&gacc[g * 2 + cc], s);
        }
    }
    __syncthreads();
    if (gspan <= 64 && t < gspan * 2) {
        int gg = t >> 1, c2 = t & 1;
        float v = gred[gg][c2];
        if (v != 0.f) atomicAdd(&gacc[(gmin + gg) * 2 + c2], v);
    }
}

// K7: finalize (counts from boundary diffs)
__global__ void k_fin(const float* __restrict__ gacc, const int* __restrict__ bnd,
                      const float* __restrict__ bc, float* __restrict__ out) {
    int t = blockIdx.x * blockDim.x + threadIdx.x;
    if (t < N_GRAPHS * 2) {
        int g = t >> 1, c = t & 1;
        int cnt = bnd[g + 1] - bnd[g];
        out[t] = gacc[t] / (float)(cnt > 1 ? cnt : 1) + bc[c];
    }
}

extern "C" void kernel_launch(void* const* d_in, const int* in_sizes, int n_in,
                              void* d_out, int out_size, void* d_ws, size_t ws_size,
                              hipStream_t stream) {
    const float* x  = (const float*)d_in[0];
    const int* ei   = (const int*)d_in[1];
    const int* batch= (const int*)d_in[2];
    const float* Wl = (const float*)d_in[3];
    const float* bl = (const float*)d_in[4];
    const float* Wr = (const float*)d_in[5];
    const float* Wc = (const float*)d_in[6];
    const float* bc = (const float*)d_in[7];
    float* out = (float*)d_out;

    char* ws = (char*)d_ws;
    float* gacc        = (float*)(ws + OFF_GACC);
    int* base          = (int*)(ws + OFF_BASE);
    ushort_t* counts   = (ushort_t*)(ws + OFF_COUNTS);
    unsigned int* sd   = (unsigned int*)(ws + OFF_SD);
    int* srcs          = (int*)(ws + OFF_SRC);
    ushort_t* xb       = (ushort_t*)(ws + OFF_SRC);  // overlays srcs after gather
    unsigned char* x8  = (unsigned char*)(ws + OFF_X8);
    int* ep            = (int*)(ws + OFF_EP);
    ushort_t* agg      = (ushort_t*)(ws + OFF_EP);   // overlays dead ep
    ushort_t* WT       = (ushort_t*)(ws + OFF_WT);
    int* bnd           = (int*)(ws + OFF_BND);

    hipMemsetAsync(ws, 0, ZBYTES, stream);
    k_count      <<<NBLK, 256, 0, stream>>>(ei, counts);
    k_scan_col   <<<NB, 256, 0, stream>>>(counts, base);
    k_scan_bucket<<<1, 512, 0, stream>>>(base);
    k_scatter    <<<NBLK, 256, 0, stream>>>(ei, counts, base, ep);
    k_csr        <<<NB, 256, 0, stream>>>(ep, base, srcs, sd);
    k_buildW     <<<(HID * 128) / 256, 256, 0, stream>>>(Wl, Wr, WT);
    k_conv8      <<<(N_NODES * 64 + 255) / 256, 256, 0, stream>>>(x, x8);
    k_bounds     <<<(N_NODES + 255) / 256, 256, 0, stream>>>(batch, bnd);
    k_gather8    <<<(N_NODES + 3) / 4, 256, 0, stream>>>(x8, sd, srcs, agg);
    k_convb      <<<(N_NODES * 16 + 255) / 256, 256, 0, stream>>>(x, xb);
    k_gemm       <<<(N_NODES + 63) / 64, 256, 0, stream>>>(agg, xb, WT, bl, Wc, batch, gacc);
    k_fin        <<<4, 256, 0, stream>>>(gacc, bnd, bc, out);
}

// Round 6
// 260.579 us; speedup vs baseline: 1.0184x; 1.0184x over previous
//
#include <hip/hip_runtime.h>

#define N_NODES 100000
#define N_EDGES 3200000
#define N_GRAPHS 512
#define IN_CH 50
#define HID 256
#define NB 391          // buckets of 256 nodes
#define NBLK 196        // edge blocks
#define EPB 16384       // edges per block

typedef unsigned short ushort_t;
using s16x8 = __attribute__((ext_vector_type(8))) short;
using us8   = __attribute__((ext_vector_type(8))) unsigned short;
using us4   = __attribute__((ext_vector_type(4))) unsigned short;
using f32x4 = __attribute__((ext_vector_type(4))) float;
using f32x2 = __attribute__((ext_vector_type(2))) float;

__device__ __forceinline__ float bf2f(ushort_t u) {
    return __uint_as_float(((unsigned int)u) << 16);
}
__device__ __forceinline__ ushort_t f2bf(float f) {
    unsigned int x = __float_as_uint(f);
    unsigned int r = x + 0x7fffu + ((x >> 16) & 1u);
    return (ushort_t)(r >> 16);
}
__device__ __forceinline__ int clampi(int v, int hi) {
    return v < 0 ? 0 : (v >= hi ? hi - 1 : v);
}

// fp8 e4m3fn encode (RNE, saturate to 448) / decode
__device__ __forceinline__ unsigned char f2e4(float f) {
    unsigned char s = (unsigned char)((__float_as_uint(f) >> 31) << 7);
    float a = fabsf(f);
    if (a >= 0.015625f) {
        if (a > 448.f) a = 448.f;
        unsigned int u = __float_as_uint(a);
        u += 0x7FFFFu + ((u >> 20) & 1u);     // RNE into 3-bit mantissa
        int e8 = (int)(u >> 23) - 127 + 7;
        unsigned int m8 = (u >> 20) & 7u;
        if (e8 > 15) { e8 = 15; m8 = 6; }
        return s | (unsigned char)((e8 << 3) | m8);
    } else {
        int m = (int)rintf(a * 512.f);
        if (m > 7) return s | 0x08;
        return s | (unsigned char)m;
    }
}
// branchless e4m3 -> f32: exact for normals AND denormals (bit-place + 2^120 scale)
__device__ __forceinline__ float e42f(unsigned int c) {
    unsigned int w = ((c & 0x80u) << 24) | ((c & 0x7fu) << 20);
    return __uint_as_float(w) * 0x1p120f;
}

// Packed fp8 decode + packed FMA accumulate into f32x2 pairs.
// a2[2i]   holds channels {4i+0, 4i+1} ... layout: a2[0..3] = 8 channels.
#if __has_builtin(__builtin_amdgcn_cvt_pk_f32_fp8)
#define ACC4(w, m, pb)                                                     \
    do {                                                                   \
        f32x2 p01 = __builtin_amdgcn_cvt_pk_f32_fp8((int)(w), false);      \
        f32x2 p23 = __builtin_amdgcn_cvt_pk_f32_fp8((int)(w), true);       \
        a2[(pb) + 0] = p01 * (m) + a2[(pb) + 0];                           \
        a2[(pb) + 1] = p23 * (m) + a2[(pb) + 1];                           \
    } while (0)
#else
#define ACC4(w, m, pb)                                                     \
    do {                                                                   \
        f32x2 p01, p23;                                                    \
        p01[0] = e42f((w) & 0xffu);        p01[1] = e42f(((w) >> 8) & 0xffu);  \
        p23[0] = e42f(((w) >> 16) & 0xffu); p23[1] = e42f(((w) >> 24) & 0xffu); \
        a2[(pb) + 0] = p01 * (m) + a2[(pb) + 0];                           \
        a2[(pb) + 1] = p23 * (m) + a2[(pb) + 1];                           \
    } while (0)
#endif

// ---- workspace layout (bytes), total 32,629,124 (proven ws_size >= 39,272,064) ----
constexpr size_t OFF_GACC   = 0;          // 512*2*4 = 4096
constexpr size_t OFF_BASE   = 6144;       // (NB+1)*4 = 1568
constexpr size_t ZBYTES     = 8192;       // zeroed prefix
constexpr size_t OFF_COUNTS = 8192;       // u16 [NBLK][NB] = 153272 -> pad 161536
constexpr size_t OFF_SD     = 161536;     // packed (start<<10|deg) u32 [N] = 400000
constexpr size_t OFF_SRC    = 561536;     // int [E] = 12.8MB; xb bf16 [N,64] overlays after gather
constexpr size_t OFF_X8     = 13361536;   // fp8 [N,64] = 6.4MB
constexpr size_t OFF_EP     = 19761536;   // epairs int [E] = 12.8MB; agg bf16 [N,64] overlays
constexpr size_t OFF_WT     = 32561536;   // bf16 [256][128] = 65536 -> end 32,627,072
constexpr size_t OFF_BND    = 32627072;   // int [N_GRAPHS+1] = 2052 (no zero-init needed)

// P1: per-(block,bucket) edge counts via LDS histogram
__global__ __launch_bounds__(256) void k_count(const int* __restrict__ ei,
                                               ushort_t* __restrict__ counts) {
    __shared__ int h[NB];
    int blk = blockIdx.x, t = threadIdx.x;
    for (int i = t; i < NB; i += 256) h[i] = 0;
    __syncthreads();
    int e0 = blk * EPB;
    for (int i = 0; i < EPB; i += 256) {
        int e = e0 + i + t;
        if (e < N_EDGES) {
            int d = clampi(ei[N_EDGES + e], N_NODES);
            atomicAdd(&h[d >> 8], 1);
        }
    }
    __syncthreads();
    for (int i = t; i < NB; i += 256) counts[blk * NB + i] = (ushort_t)h[i];
}

// P2a: per-bucket column scan
__global__ __launch_bounds__(256) void k_scan_col(ushort_t* __restrict__ counts,
                                                  int* __restrict__ base) {
    __shared__ int a[256];
    __shared__ int orig[256];
    int b = blockIdx.x, t = threadIdx.x;
    int v = (t < NBLK) ? (int)counts[t * NB + b] : 0;
    orig[t] = v; a[t] = v;
    __syncthreads();
    for (int off = 1; off < 256; off <<= 1) {
        int u = (t >= off) ? a[t - off] : 0;
        __syncthreads();
        a[t] += u;
        __syncthreads();
    }
    if (t < NBLK) counts[t * NB + b] = (ushort_t)(a[t] - orig[t]);
    if (t == 255) base[b] = a[255];
}

// P2b: exclusive scan over bucket totals
__global__ __launch_bounds__(512) void k_scan_bucket(int* __restrict__ base) {
    __shared__ int a[512];
    __shared__ int orig[512];
    int t = threadIdx.x;
    int v = (t < NB) ? base[t] : 0;
    orig[t] = v; a[t] = v;
    __syncthreads();
    for (int off = 1; off < 512; off <<= 1) {
        int u = (t >= off) ? a[t - off] : 0;
        __syncthreads();
        a[t] += u;
        __syncthreads();
    }
    if (t < NB) base[t] = a[t] - orig[t];
    if (t == NB - 1) base[NB] = a[t];
}

// P3: scatter edges into bucket-contiguous runs; pack (src<<8)|dst_local
__global__ __launch_bounds__(256) void k_scatter(const int* __restrict__ ei,
                                                 const ushort_t* __restrict__ counts,
                                                 const int* __restrict__ base,
                                                 int* __restrict__ ep) {
    __shared__ int rnk[NB];
    __shared__ int ob[NB];
    int blk = blockIdx.x, t = threadIdx.x;
    for (int i = t; i < NB; i += 256) {
        rnk[i] = 0;
        ob[i] = base[i] + (int)counts[blk * NB + i];
    }
    __syncthreads();
    int e0 = blk * EPB;
    for (int i = 0; i < EPB; i += 256) {
        int e = e0 + i + t;
        if (e < N_EDGES) {
            int s = clampi(ei[e], N_NODES);
            int d = clampi(ei[N_EDGES + e], N_NODES);
            int b = d >> 8;
            int r = atomicAdd(&rnk[b], 1);
            ep[ob[b] + r] = (s << 8) | (d & 255);
        }
    }
}

// P4: per-bucket fine CSR; emit packed start|deg
__global__ __launch_bounds__(256) void k_csr(const int* __restrict__ ep,
                                             const int* __restrict__ base,
                                             int* __restrict__ srcs,
                                             unsigned int* __restrict__ sd) {
    __shared__ int ldeg[256];
    __shared__ int a[256];
    __shared__ int lcur[256];
    int b = blockIdx.x, t = threadIdx.x;
    int e0 = base[b], e1 = base[b + 1];
    ldeg[t] = 0;
    __syncthreads();
    for (int e = e0 + t; e < e1; e += 256) atomicAdd(&ldeg[ep[e] & 255], 1);
    __syncthreads();
    a[t] = ldeg[t];
    __syncthreads();
    for (int off = 1; off < 256; off <<= 1) {
        int u = (t >= off) ? a[t - off] : 0;
        __syncthreads();
        a[t] += u;
        __syncthreads();
    }
    int excl = a[t] - ldeg[t];
    lcur[t] = excl;
    __syncthreads();
    int n = (b << 8) + t;
    if (n < N_NODES) {
        int dgc = ldeg[t] < 1023 ? ldeg[t] : 1023;
        sd[n] = ((unsigned int)(e0 + excl) << 10) | (unsigned int)dgc;
    }
    for (int e = e0 + t; e < e1; e += 256) {
        int p = ep[e];
        int dl = p & 255;
        int r = atomicAdd(&lcur[dl], 1);
        srcs[e0 + r] = p >> 8;
    }
}

// K4 fused prep: [0,25000) conv8 | [25000,25128) buildW | [25128,25519) bounds
#define PREP_CONV_BLOCKS 25000
#define PREP_BW_BLOCKS 128
#define PREP_BND_BLOCKS 391
__global__ __launch_bounds__(256) void k_prep(const float* __restrict__ x,
                                              unsigned char* __restrict__ x8,
                                              const float* __restrict__ Wl,
                                              const float* __restrict__ Wr,
                                              ushort_t* __restrict__ WT,
                                              const int* __restrict__ batch,
                                              int* __restrict__ bnd) {
    int blk = blockIdx.x;
    if (blk < PREP_CONV_BLOCKS) {
        int t = blk * 256 + threadIdx.x;
        int n = t >> 6, c = t & 63;
        x8[t] = (c < IN_CH) ? f2e4(x[n * IN_CH + c]) : (unsigned char)0;
    } else if (blk < PREP_CONV_BLOCKS + PREP_BW_BLOCKS) {
        int idx = (blk - PREP_CONV_BLOCKS) * 256 + threadIdx.x;
        int j = idx >> 7;
        int k = idx & 127;
        ushort_t val = 0;
        if (k < IN_CH) val = f2bf(Wl[j * IN_CH + k]);
        else if (k >= 64 && k < 64 + IN_CH) val = f2bf(Wr[j * IN_CH + (k - 64)]);
        WT[idx] = val;
    } else {
        int n = (blk - PREP_CONV_BLOCKS - PREP_BW_BLOCKS) * 256 + threadIdx.x;
        if (n >= N_NODES) return;
        int b = clampi(batch[n], N_GRAPHS);
        if (n == 0) {
            for (int g = 0; g <= b; ++g) bnd[g] = 0;
        } else {
            int a = clampi(batch[n - 1], N_GRAPHS);
            for (int g = a + 1; g <= b; ++g) bnd[g] = n;
        }
        if (n == N_NODES - 1) {
            for (int g = b + 1; g <= N_GRAPHS; ++g) bnd[g] = N_NODES;
        }
    }
}

// K4d: x fp32 [N,50] -> xb bf16 [N,64] (cols 50..63 = 0); us4-vectorized stores.
// Runs AFTER k_gather8 (overlays dead srcs region).
__global__ __launch_bounds__(256) void k_convb(const float* __restrict__ x,
                                               ushort_t* __restrict__ xb) {
    int t = blockIdx.x * blockDim.x + threadIdx.x;
    if (t >= N_NODES * 16) return;
    int n = t >> 4, c4 = (t & 15) << 2;
    us4 o;
#pragma unroll
    for (int j = 0; j < 4; j++) {
        int c = c4 + j;
        o[j] = (c < IN_CH) ? f2bf(x[n * IN_CH + c]) : (ushort_t)0;
    }
    *(us4*)(xb + (size_t)n * 64 + c4) = o;
}

// K5 v5: wave-per-node gather mean from fp8 x8; packed cvt + packed FMA.
__global__ __launch_bounds__(256) void k_gather8(const unsigned char* __restrict__ x8,
                          const unsigned int* __restrict__ sd,
                          const int* __restrict__ srcs, ushort_t* __restrict__ agg) {
    int gid = (blockIdx.x * blockDim.x + threadIdx.x) >> 6;
    int lane = threadIdx.x & 63;
    if (gid >= N_NODES) return;
    int r8 = lane >> 3;          // row within group of 8
    int c8 = lane & 7;           // byte-octet within 64B row
    unsigned int v = sd[gid];
    int dg = (int)(v & 1023u);
    int st = (int)(v >> 10);

    f32x2 a2[4] = {};            // 8 channels as 4 packed pairs

    const int nit = (dg + 31) >> 5;
    const int cb = c8 << 3;      // byte offset within row
    for (int it = 0; it < nit; ++it) {
        int i0 = (it << 5) + r8;
        int i1 = i0 + 8, i2 = i0 + 16, i3 = i0 + 24;
        int s0 = srcs[st + (i0 < dg ? i0 : 0)];
        int s1 = srcs[st + (i1 < dg ? i1 : 0)];
        int s2 = srcs[st + (i2 < dg ? i2 : 0)];
        int s3 = srcs[st + (i3 < dg ? i3 : 0)];
        uint2 w0 = *(const uint2*)(x8 + (size_t)s0 * 64 + cb);
        uint2 w1 = *(const uint2*)(x8 + (size_t)s1 * 64 + cb);
        uint2 w2 = *(const uint2*)(x8 + (size_t)s2 * 64 + cb);
        uint2 w3 = *(const uint2*)(x8 + (size_t)s3 * 64 + cb);
        float m0 = i0 < dg ? 1.f : 0.f;
        float m1 = i1 < dg ? 1.f : 0.f;
        float m2 = i2 < dg ? 1.f : 0.f;
        float m3 = i3 < dg ? 1.f : 0.f;
        ACC4(w0.x, m0, 0); ACC4(w0.y, m0, 2);
        ACC4(w1.x, m1, 0); ACC4(w1.y, m1, 2);
        ACC4(w2.x, m2, 0); ACC4(w2.y, m2, 2);
        ACC4(w3.x, m3, 0); ACC4(w3.y, m3, 2);
    }

    // reduce across the 8 row-groups (lanes differing in bits 3..5)
#pragma unroll
    for (int p = 0; p < 4; ++p) {
        a2[p][0] += __shfl_xor(a2[p][0], 8);
        a2[p][1] += __shfl_xor(a2[p][1], 8);
        a2[p][0] += __shfl_xor(a2[p][0], 16);
        a2[p][1] += __shfl_xor(a2[p][1], 16);
        a2[p][0] += __shfl_xor(a2[p][0], 32);
        a2[p][1] += __shfl_xor(a2[p][1], 32);
    }
    float inv = 1.0f / (float)(dg > 1 ? dg : 1);
    if (r8 == 0) {
        us8 o;
#pragma unroll
        for (int b = 0; b < 8; ++b) o[b] = f2bf(a2[b >> 1][b & 1] * inv);
        *(us8*)(agg + (size_t)gid * 64 + cb) = o;
    }
}

// K6 v3: fused MFMA GEMM, 256 rows/block (4 A-tile rounds reuse in-register B).
// B (constant WT) in registers per wave; per-graph LDS reduce across rounds.
__global__ __launch_bounds__(256) void k_gemm(const ushort_t* __restrict__ agg,
                                              const ushort_t* __restrict__ xb,
                                              const ushort_t* __restrict__ WT,
                                              const float* __restrict__ bl,
                                              const float* __restrict__ Wc,
                                              const int* __restrict__ batch,
                                              float* __restrict__ gacc) {
    __shared__ ushort_t Alds[64 * 136];   // row stride 136 shorts (pad 8)
    __shared__ float ypart[4][64][2];
    __shared__ float gred[64][2];

    const int t = threadIdx.x;
    const int w = t >> 6;
    const int lane = t & 63;
    const int quad = lane >> 4;
    const int r16 = lane & 15;
    const int brow0 = blockIdx.x * 256;

    if (t < 128) gred[t >> 1][t & 1] = 0.f;

    // B-fragments: wave w covers cols w*64 + 16*ni + r16; k = s*32 + quad*8 .. +7
    s16x8 bfr[4][4];
#pragma unroll
    for (int s = 0; s < 4; ++s)
#pragma unroll
        for (int ni = 0; ni < 4; ++ni)
            bfr[s][ni] = *(const s16x8*)(WT + (size_t)(w * 64 + 16 * ni + r16) * 128
                                            + s * 32 + (quad << 3));

    float blv[4], w0v[4], w1v[4];
#pragma unroll
    for (int ni = 0; ni < 4; ni++) {
        int col = w * 64 + 16 * ni + r16;
        blv[ni] = bl[col];
        w0v[ni] = Wc[col];
        w1v[ni] = Wc[HID + col];
    }

    int lastb = brow0 + 255;
    if (lastb >= N_NODES) lastb = N_NODES - 1;
    const int gmin = clampi(batch[brow0], N_GRAPHS);
    const int gmax = clampi(batch[lastb], N_GRAPHS);
    const int gspan = gmax - gmin + 1;
    const bool use_lds = (gspan <= 64);

    for (int r4 = 0; r4 < 4; ++r4) {
        const int row0 = brow0 + r4 * 64;
        __syncthreads();   // Alds/ypart safe to overwrite (covers gred init on r4==0)
        {
            int row = t >> 2;
            int q4 = t & 3;
            int gr = row0 + row;
            us8* dst = (us8*)&Alds[row * 136 + q4 * 32];
            if (gr < N_NODES) {
                const us8* src = (q4 < 2)
                    ? (const us8*)(agg + (size_t)gr * 64 + (q4 & 1) * 32)
                    : (const us8*)(xb + (size_t)gr * 64 + (q4 & 1) * 32);
                dst[0] = src[0];
                dst[1] = src[1];
                dst[2] = src[2];
                dst[3] = src[3];
            } else {
                us8 z = {0, 0, 0, 0, 0, 0, 0, 0};
                dst[0] = z; dst[1] = z; dst[2] = z; dst[3] = z;
            }
        }
        __syncthreads();

        f32x4 acc[4][4] = {};
#pragma unroll
        for (int s = 0; s < 4; ++s) {
            s16x8 af[4];
#pragma unroll
            for (int mi = 0; mi < 4; mi++)
                af[mi] = *(const s16x8*)&Alds[(16 * mi + r16) * 136 + s * 32 + (quad << 3)];
#pragma unroll
            for (int mi = 0; mi < 4; mi++)
#pragma unroll
                for (int ni = 0; ni < 4; ni++)
                    acc[mi][ni] = __builtin_amdgcn_mfma_f32_16x16x32_bf16(
                        af[mi], bfr[s][ni], acc[mi][ni], 0, 0, 0);
        }

#pragma unroll
        for (int mi = 0; mi < 4; mi++) {
#pragma unroll
            for (int r = 0; r < 4; r++) {
                float p0 = 0.f, p1 = 0.f;
#pragma unroll
                for (int ni = 0; ni < 4; ni++) {
                    float h = acc[mi][ni][r] + blv[ni];
                    h = (h > 0.f) ? h : 0.01f * h;
                    p0 = fmaf(h, w0v[ni], p0);
                    p1 = fmaf(h, w1v[ni], p1);
                }
#pragma unroll
                for (int off = 1; off < 16; off <<= 1) {
                    p0 += __shfl_xor(p0, off, 16);
                    p1 += __shfl_xor(p1, off, 16);
                }
                if (r16 == 0) {
                    int rl = 16 * mi + (quad << 2) + r;
                    ypart[w][rl][0] = p0;
                    ypart[w][rl][1] = p1;
                }
            }
        }
        __syncthreads();

        if (t < 128) {
            int rl = t >> 1, cc = t & 1;
            int node = row0 + rl;
            if (node < N_NODES) {
                float s = ypart[0][rl][cc] + ypart[1][rl][cc]
                        + ypart[2][rl][cc] + ypart[3][rl][cc];
                int g = clampi(batch[node], N_GRAPHS);
                if (use_lds) atomicAdd(&gred[g - gmin][cc], s);
                else atomicAdd(&gacc[g * 2 + cc], s);
            }
        }
    }
    __syncthreads();
    if (use_lds && t < gspan * 2) {
        int gg = t >> 1, c2 = t & 1;
        float v = gred[gg][c2];
        if (v != 0.f) atomicAdd(&gacc[(gmin + gg) * 2 + c2], v);
    }
}

// K7: finalize (counts from boundary diffs)
__global__ void k_fin(const float* __restrict__ gacc, const int* __restrict__ bnd,
                      const float* __restrict__ bc, float* __restrict__ out) {
    int t = blockIdx.x * blockDim.x + threadIdx.x;
    if (t < N_GRAPHS * 2) {
        int g = t >> 1, c = t & 1;
        int cnt = bnd[g + 1] - bnd[g];
        out[t] = gacc[t] / (float)(cnt > 1 ? cnt : 1) + bc[c];
    }
}

extern "C" void kernel_launch(void* const* d_in, const int* in_sizes, int n_in,
                              void* d_out, int out_size, void* d_ws, size_t ws_size,
                              hipStream_t stream) {
    const float* x  = (const float*)d_in[0];
    const int* ei   = (const int*)d_in[1];
    const int* batch= (const int*)d_in[2];
    const float* Wl = (const float*)d_in[3];
    const float* bl = (const float*)d_in[4];
    const float* Wr = (const float*)d_in[5];
    const float* Wc = (const float*)d_in[6];
    const float* bc = (const float*)d_in[7];
    float* out = (float*)d_out;

    char* ws = (char*)d_ws;
    float* gacc        = (float*)(ws + OFF_GACC);
    int* base          = (int*)(ws + OFF_BASE);
    ushort_t* counts   = (ushort_t*)(ws + OFF_COUNTS);
    unsigned int* sd   = (unsigned int*)(ws + OFF_SD);
    int* srcs          = (int*)(ws + OFF_SRC);
    ushort_t* xb       = (ushort_t*)(ws + OFF_SRC);  // overlays srcs after gather
    unsigned char* x8  = (unsigned char*)(ws + OFF_X8);
    int* ep            = (int*)(ws + OFF_EP);
    ushort_t* agg      = (ushort_t*)(ws + OFF_EP);   // overlays dead ep
    ushort_t* WT       = (ushort_t*)(ws + OFF_WT);
    int* bnd           = (int*)(ws + OFF_BND);

    hipMemsetAsync(ws, 0, ZBYTES, stream);
    k_count      <<<NBLK, 256, 0, stream>>>(ei, counts);
    k_scan_col   <<<NB, 256, 0, stream>>>(counts, base);
    k_scan_bucket<<<1, 512, 0, stream>>>(base);
    k_scatter    <<<NBLK, 256, 0, stream>>>(ei, counts, base, ep);
    k_csr        <<<NB, 256, 0, stream>>>(ep, base, srcs, sd);
    k_prep       <<<PREP_CONV_BLOCKS + PREP_BW_BLOCKS + PREP_BND_BLOCKS, 256, 0, stream>>>(
                     x, x8, Wl, Wr, WT, batch, bnd);
    k_gather8    <<<(N_NODES + 3) / 4, 256, 0, stream>>>(x8, sd, srcs, agg);
    k_convb      <<<(N_NODES * 16 + 255) / 256, 256, 0, stream>>>(x, xb);
    k_gemm       <<<(N_NODES + 255) / 256, 256, 0, stream>>>(agg, xb, WT, bl, Wc, batch, gacc);
    k_fin        <<<4, 256, 0, stream>>>(gacc, bnd, bc, out);
}

// Round 8
// 258.557 us; speedup vs baseline: 1.0263x; 1.0078x over previous
//
#include <hip/hip_runtime.h>

#define N_NODES 100000
#define N_EDGES 3200000
#define N_GRAPHS 512
#define IN_CH 50
#define HID 256
#define NB 391          // buckets of 256 nodes
#define NBLK 196        // edge blocks
#define EPB 16384       // edges per block

typedef unsigned short ushort_t;
using s16x8 = __attribute__((ext_vector_type(8))) short;
using us8   = __attribute__((ext_vector_type(8))) unsigned short;
using us4   = __attribute__((ext_vector_type(4))) unsigned short;
using f32x4 = __attribute__((ext_vector_type(4))) float;
using f32x2 = __attribute__((ext_vector_type(2))) float;

__device__ __forceinline__ float bf2f(ushort_t u) {
    return __uint_as_float(((unsigned int)u) << 16);
}
__device__ __forceinline__ ushort_t f2bf(float f) {
    unsigned int x = __float_as_uint(f);
    unsigned int r = x + 0x7fffu + ((x >> 16) & 1u);
    return (ushort_t)(r >> 16);
}
__device__ __forceinline__ int clampi(int v, int hi) {
    return v < 0 ? 0 : (v >= hi ? hi - 1 : v);
}

// fp8 e4m3fn encode (RNE, saturate to 448) / decode
__device__ __forceinline__ unsigned char f2e4(float f) {
    unsigned char s = (unsigned char)((__float_as_uint(f) >> 31) << 7);
    float a = fabsf(f);
    if (a >= 0.015625f) {
        if (a > 448.f) a = 448.f;
        unsigned int u = __float_as_uint(a);
        u += 0x7FFFFu + ((u >> 20) & 1u);     // RNE into 3-bit mantissa
        int e8 = (int)(u >> 23) - 127 + 7;
        unsigned int m8 = (u >> 20) & 7u;
        if (e8 > 15) { e8 = 15; m8 = 6; }
        return s | (unsigned char)((e8 << 3) | m8);
    } else {
        int m = (int)rintf(a * 512.f);
        if (m > 7) return s | 0x08;
        return s | (unsigned char)m;
    }
}
// branchless e4m3 -> f32: exact for normals AND denormals (bit-place + 2^120 scale)
__device__ __forceinline__ float e42f(unsigned int c) {
    unsigned int w = ((c & 0x80u) << 24) | ((c & 0x7fu) << 20);
    return __uint_as_float(w) * 0x1p120f;
}

// Packed fp8 decode + packed FMA accumulate into f32x2 pairs.
#if __has_builtin(__builtin_amdgcn_cvt_pk_f32_fp8)
#define ACC4(w, m, pb)                                                     \
    do {                                                                   \
        f32x2 p01 = __builtin_amdgcn_cvt_pk_f32_fp8((int)(w), false);      \
        f32x2 p23 = __builtin_amdgcn_cvt_pk_f32_fp8((int)(w), true);       \
        a2[(pb) + 0] = p01 * (m) + a2[(pb) + 0];                           \
        a2[(pb) + 1] = p23 * (m) + a2[(pb) + 1];                           \
    } while (0)
#else
#define ACC4(w, m, pb)                                                     \
    do {                                                                   \
        f32x2 p01, p23;                                                    \
        p01[0] = e42f((w) & 0xffu);        p01[1] = e42f(((w) >> 8) & 0xffu);  \
        p23[0] = e42f(((w) >> 16) & 0xffu); p23[1] = e42f(((w) >> 24) & 0xffu); \
        a2[(pb) + 0] = p01 * (m) + a2[(pb) + 0];                           \
        a2[(pb) + 1] = p23 * (m) + a2[(pb) + 1];                           \
    } while (0)
#endif

// ---- workspace layout (bytes), total 32,629,124 (proven ws_size >= 39,272,064) ----
constexpr size_t OFF_GACC   = 0;          // 512*2*4 = 4096
constexpr size_t OFF_BASE   = 6144;       // (NB+1)*4 = 1568
constexpr size_t ZBYTES     = 8192;       // zeroed prefix
constexpr size_t OFF_COUNTS = 8192;       // u16 [NBLK][NB] = 153272 -> pad 161536
constexpr size_t OFF_SD     = 161536;     // packed (start<<10|deg) u32 [N] = 400000
constexpr size_t OFF_SRC    = 561536;     // int [E] = 12.8MB; xb bf16 [N,64] overlays after gather
constexpr size_t OFF_X8     = 13361536;   // fp8 [N,64] = 6.4MB
constexpr size_t OFF_EP     = 19761536;   // epairs int [E] = 12.8MB; agg bf16 [N,64] overlays
constexpr size_t OFF_WT     = 32561536;   // bf16 [256][128] = 65536 -> end 32,627,072
constexpr size_t OFF_BND    = 32627072;   // int [N_GRAPHS+1] = 2052 (no zero-init needed)

// P1: per-(block,bucket) edge counts via LDS histogram
__global__ __launch_bounds__(256) void k_count(const int* __restrict__ ei,
                                               ushort_t* __restrict__ counts) {
    __shared__ int h[NB];
    int blk = blockIdx.x, t = threadIdx.x;
    for (int i = t; i < NB; i += 256) h[i] = 0;
    __syncthreads();
    int e0 = blk * EPB;
    for (int i = 0; i < EPB; i += 256) {
        int e = e0 + i + t;
        if (e < N_EDGES) {
            int d = clampi(ei[N_EDGES + e], N_NODES);
            atomicAdd(&h[d >> 8], 1);
        }
    }
    __syncthreads();
    for (int i = t; i < NB; i += 256) counts[blk * NB + i] = (ushort_t)h[i];
}

// P2a: per-bucket column scan
__global__ __launch_bounds__(256) void k_scan_col(ushort_t* __restrict__ counts,
                                                  int* __restrict__ base) {
    __shared__ int a[256];
    __shared__ int orig[256];
    int b = blockIdx.x, t = threadIdx.x;
    int v = (t < NBLK) ? (int)counts[t * NB + b] : 0;
    orig[t] = v; a[t] = v;
    __syncthreads();
    for (int off = 1; off < 256; off <<= 1) {
        int u = (t >= off) ? a[t - off] : 0;
        __syncthreads();
        a[t] += u;
        __syncthreads();
    }
    if (t < NBLK) counts[t * NB + b] = (ushort_t)(a[t] - orig[t]);
    if (t == 255) base[b] = a[255];
}

// P2b: exclusive scan over bucket totals
__global__ __launch_bounds__(512) void k_scan_bucket(int* __restrict__ base) {
    __shared__ int a[512];
    __shared__ int orig[512];
    int t = threadIdx.x;
    int v = (t < NB) ? base[t] : 0;
    orig[t] = v; a[t] = v;
    __syncthreads();
    for (int off = 1; off < 512; off <<= 1) {
        int u = (t >= off) ? a[t - off] : 0;
        __syncthreads();
        a[t] += u;
        __syncthreads();
    }
    if (t < NB) base[t] = a[t] - orig[t];
    if (t == NB - 1) base[NB] = a[t];
}

// P3 v2: LDS counting-sort per half-block (8192 edges), then COALESCED flush.
// Edges held in registers (16/thread); per-(block,bucket) runs are contiguous in
// global, written wave-per-run. Replaces random 4B global stores (64B-line
// write amplification) with sequential runs.
__global__ __launch_bounds__(512) void k_scatter(const int* __restrict__ ei,
                                                 const ushort_t* __restrict__ counts,
                                                 const int* __restrict__ base,
                                                 int* __restrict__ ep) {
    __shared__ int hist[NB];
    __shared__ int sa[512];
    __shared__ int sorig[512];
    __shared__ int lstart[NB + 1];
    __shared__ int lcur[NB];
    __shared__ int gcur[NB];
    __shared__ unsigned int eph[8192];

    const int blk = blockIdx.x, t = threadIdx.x;
    for (int i = t; i < NB; i += 512)
        gcur[i] = base[i] + (int)counts[blk * NB + i];
    const int e0 = blk * EPB;

    for (int h = 0; h < 2; ++h) {
        for (int i = t; i < NB; i += 512) hist[i] = 0;
        __syncthreads();
        const int hb = e0 + h * 8192;
        int sv[16], dv[16];
#pragma unroll
        for (int j = 0; j < 16; ++j) {
            int e = hb + j * 512 + t;
            if (e < N_EDGES) {
                sv[j] = clampi(ei[e], N_NODES);
                dv[j] = clampi(ei[N_EDGES + e], N_NODES);
            } else {
                dv[j] = -1;
            }
        }
#pragma unroll
        for (int j = 0; j < 16; ++j)
            if (dv[j] >= 0) atomicAdd(&hist[dv[j] >> 8], 1);
        __syncthreads();
        // 512-wide Hillis-Steele scan over NB buckets -> exclusive lstart
        int v = (t < NB) ? hist[t] : 0;
        sa[t] = v; sorig[t] = v;
        __syncthreads();
        for (int off = 1; off < 512; off <<= 1) {
            int u = (t >= off) ? sa[t - off] : 0;
            __syncthreads();
            sa[t] += u;
            __syncthreads();
        }
        if (t < NB) { lstart[t] = sa[t] - sorig[t]; lcur[t] = sa[t] - sorig[t]; }
        if (t == NB - 1) lstart[NB] = sa[t];
        __syncthreads();
        // place into LDS (cheap random LDS writes)
#pragma unroll
        for (int j = 0; j < 16; ++j) {
            if (dv[j] >= 0) {
                int b = dv[j] >> 8;
                int r = atomicAdd(&lcur[b], 1);
                eph[r] = ((unsigned int)sv[j] << 8) | (unsigned int)(dv[j] & 255);
            }
        }
        __syncthreads();
        // coalesced flush: wave per bucket-run (runs contiguous in global)
        {
            int wid = t >> 6, lane = t & 63;
            for (int b = wid; b < NB; b += 8) {
                int s = lstart[b], eN = lstart[b + 1];
                int g = gcur[b];
                for (int i = s + lane; i < eN; i += 64)
                    ep[g + (i - s)] = (int)eph[i];
            }
        }
        __syncthreads();
        for (int i = t; i < NB; i += 512) gcur[i] += lstart[i + 1] - lstart[i];
        __syncthreads();
    }
}

// P4 v2: per-bucket fine CSR; srcs staged in LDS then flushed coalesced.
// Bucket size ~ Binomial(3.2M, 1/391): 8184 +/- 92 -> 10240 cap = +22 sigma.
#define CSR_CAP 10240
__global__ __launch_bounds__(256) void k_csr(const int* __restrict__ ep,
                                             const int* __restrict__ base,
                                             int* __restrict__ srcs,
                                             unsigned int* __restrict__ sd) {
    __shared__ int ldeg[256];
    __shared__ int a[256];
    __shared__ int lcur[256];
    __shared__ int lds_src[CSR_CAP];
    int b = blockIdx.x, t = threadIdx.x;
    int e0 = base[b], e1 = base[b + 1];
    int m = e1 - e0;
    ldeg[t] = 0;
    __syncthreads();
    for (int e = e0 + t; e < e1; e += 256) atomicAdd(&ldeg[ep[e] & 255], 1);
    __syncthreads();
    a[t] = ldeg[t];
    __syncthreads();
    for (int off = 1; off < 256; off <<= 1) {
        int u = (t >= off) ? a[t - off] : 0;
        __syncthreads();
        a[t] += u;
        __syncthreads();
    }
    int excl = a[t] - ldeg[t];
    lcur[t] = excl;
    __syncthreads();
    int n = (b << 8) + t;
    if (n < N_NODES) {
        int dgc = ldeg[t] < 1023 ? ldeg[t] : 1023;
        sd[n] = ((unsigned int)(e0 + excl) << 10) | (unsigned int)dgc;
    }
    if (m <= CSR_CAP) {
        for (int e = e0 + t; e < e1; e += 256) {
            int p = ep[e];
            int dl = p & 255;
            int r = atomicAdd(&lcur[dl], 1);
            lds_src[r] = p >> 8;
        }
        __syncthreads();
        for (int i = t; i < m; i += 256) srcs[e0 + i] = lds_src[i];
    } else {
        // fallback (never expected): direct global scatter
        for (int e = e0 + t; e < e1; e += 256) {
            int p = ep[e];
            int dl = p & 255;
            int r = atomicAdd(&lcur[dl], 1);
            srcs[e0 + r] = p >> 8;
        }
    }
}

// K4 fused prep: [0,25000) conv8 | [25000,25128) buildW | [25128,25519) bounds
#define PREP_CONV_BLOCKS 25000
#define PREP_BW_BLOCKS 128
#define PREP_BND_BLOCKS 391
__global__ __launch_bounds__(256) void k_prep(const float* __restrict__ x,
                                              unsigned char* __restrict__ x8,
                                              const float* __restrict__ Wl,
                                              const float* __restrict__ Wr,
                                              ushort_t* __restrict__ WT,
                                              const int* __restrict__ batch,
                                              int* __restrict__ bnd) {
    int blk = blockIdx.x;
    if (blk < PREP_CONV_BLOCKS) {
        int t = blk * 256 + threadIdx.x;
        int n = t >> 6, c = t & 63;
        x8[t] = (c < IN_CH) ? f2e4(x[n * IN_CH + c]) : (unsigned char)0;
    } else if (blk < PREP_CONV_BLOCKS + PREP_BW_BLOCKS) {
        int idx = (blk - PREP_CONV_BLOCKS) * 256 + threadIdx.x;
        int j = idx >> 7;
        int k = idx & 127;
        ushort_t val = 0;
        if (k < IN_CH) val = f2bf(Wl[j * IN_CH + k]);
        else if (k >= 64 && k < 64 + IN_CH) val = f2bf(Wr[j * IN_CH + (k - 64)]);
        WT[idx] = val;
    } else {
        int n = (blk - PREP_CONV_BLOCKS - PREP_BW_BLOCKS) * 256 + threadIdx.x;
        if (n >= N_NODES) return;
        int b = clampi(batch[n], N_GRAPHS);
        if (n == 0) {
            for (int g = 0; g <= b; ++g) bnd[g] = 0;
        } else {
            int a = clampi(batch[n - 1], N_GRAPHS);
            for (int g = a + 1; g <= b; ++g) bnd[g] = n;
        }
        if (n == N_NODES - 1) {
            for (int g = b + 1; g <= N_GRAPHS; ++g) bnd[g] = N_NODES;
        }
    }
}

// K4d: x fp32 [N,50] -> xb bf16 [N,64] (cols 50..63 = 0); us4-vectorized stores.
// Runs AFTER k_gather8 (overlays dead srcs region).
__global__ __launch_bounds__(256) void k_convb(const float* __restrict__ x,
                                               ushort_t* __restrict__ xb) {
    int t = blockIdx.x * blockDim.x + threadIdx.x;
    if (t >= N_NODES * 16) return;
    int n = t >> 4, c4 = (t & 15) << 2;
    us4 o;
#pragma unroll
    for (int j = 0; j < 4; j++) {
        int c = c4 + j;
        o[j] = (c < IN_CH) ? f2bf(x[n * IN_CH + c]) : (ushort_t)0;
    }
    *(us4*)(xb + (size_t)n * 64 + c4) = o;
}

// K5 v5: wave-per-node gather mean from fp8 x8; packed cvt + packed FMA.
__global__ __launch_bounds__(256) void k_gather8(const unsigned char* __restrict__ x8,
                          const unsigned int* __restrict__ sd,
                          const int* __restrict__ srcs, ushort_t* __restrict__ agg) {
    int gid = (blockIdx.x * blockDim.x + threadIdx.x) >> 6;
    int lane = threadIdx.x & 63;
    if (gid >= N_NODES) return;
    int r8 = lane >> 3;          // row within group of 8
    int c8 = lane & 7;           // byte-octet within 64B row
    unsigned int v = sd[gid];
    int dg = (int)(v & 1023u);
    int st = (int)(v >> 10);

    f32x2 a2[4] = {};            // 8 channels as 4 packed pairs

    const int nit = (dg + 31) >> 5;
    const int cb = c8 << 3;      // byte offset within row
    for (int it = 0; it < nit; ++it) {
        int i0 = (it << 5) + r8;
        int i1 = i0 + 8, i2 = i0 + 16, i3 = i0 + 24;
        int s0 = srcs[st + (i0 < dg ? i0 : 0)];
        int s1 = srcs[st + (i1 < dg ? i1 : 0)];
        int s2 = srcs[st + (i2 < dg ? i2 : 0)];
        int s3 = srcs[st + (i3 < dg ? i3 : 0)];
        uint2 w0 = *(const uint2*)(x8 + (size_t)s0 * 64 + cb);
        uint2 w1 = *(const uint2*)(x8 + (size_t)s1 * 64 + cb);
        uint2 w2 = *(const uint2*)(x8 + (size_t)s2 * 64 + cb);
        uint2 w3 = *(const uint2*)(x8 + (size_t)s3 * 64 + cb);
        float m0 = i0 < dg ? 1.f : 0.f;
        float m1 = i1 < dg ? 1.f : 0.f;
        float m2 = i2 < dg ? 1.f : 0.f;
        float m3 = i3 < dg ? 1.f : 0.f;
        ACC4(w0.x, m0, 0); ACC4(w0.y, m0, 2);
        ACC4(w1.x, m1, 0); ACC4(w1.y, m1, 2);
        ACC4(w2.x, m2, 0); ACC4(w2.y, m2, 2);
        ACC4(w3.x, m3, 0); ACC4(w3.y, m3, 2);
    }

    // reduce across the 8 row-groups (lanes differing in bits 3..5)
#pragma unroll
    for (int p = 0; p < 4; ++p) {
        a2[p][0] += __shfl_xor(a2[p][0], 8);
        a2[p][1] += __shfl_xor(a2[p][1], 8);
        a2[p][0] += __shfl_xor(a2[p][0], 16);
        a2[p][1] += __shfl_xor(a2[p][1], 16);
        a2[p][0] += __shfl_xor(a2[p][0], 32);
        a2[p][1] += __shfl_xor(a2[p][1], 32);
    }
    float inv = 1.0f / (float)(dg > 1 ? dg : 1);
    if (r8 == 0) {
        us8 o;
#pragma unroll
        for (int b = 0; b < 8; ++b) o[b] = f2bf(a2[b >> 1][b & 1] * inv);
        *(us8*)(agg + (size_t)gid * 64 + cb) = o;
    }
}

// K6 v3: fused MFMA GEMM, 256 rows/block (4 A-tile rounds reuse in-register B).
// B (constant WT) in registers per wave; per-graph LDS reduce across rounds.
__global__ __launch_bounds__(256) void k_gemm(const ushort_t* __restrict__ agg,
                                              const ushort_t* __restrict__ xb,
                                              const ushort_t* __restrict__ WT,
                                              const float* __restrict__ bl,
                                              const float* __restrict__ Wc,
                                              const int* __restrict__ batch,
                                              float* __restrict__ gacc) {
    __shared__ ushort_t Alds[64 * 136];   // row stride 136 shorts (pad 8)
    __shared__ float ypart[4][64][2];
    __shared__ float gred[64][2];

    const int t = threadIdx.x;
    const int w = t >> 6;
    const int lane = t & 63;
    const int quad = lane >> 4;
    const int r16 = lane & 15;
    const int brow0 = blockIdx.x * 256;

    if (t < 128) gred[t >> 1][t & 1] = 0.f;

    // B-fragments: wave w covers cols w*64 + 16*ni + r16; k = s*32 + quad*8 .. +7
    s16x8 bfr[4][4];
#pragma unroll
    for (int s = 0; s < 4; ++s)
#pragma unroll
        for (int ni = 0; ni < 4; ++ni)
            bfr[s][ni] = *(const s16x8*)(WT + (size_t)(w * 64 + 16 * ni + r16) * 128
                                            + s * 32 + (quad << 3));

    float blv[4], w0v[4], w1v[4];
#pragma unroll
    for (int ni = 0; ni < 4; ni++) {
        int col = w * 64 + 16 * ni + r16;
        blv[ni] = bl[col];
        w0v[ni] = Wc[col];
        w1v[ni] = Wc[HID + col];
    }

    int lastb = brow0 + 255;
    if (lastb >= N_NODES) lastb = N_NODES - 1;
    const int gmin = clampi(batch[brow0], N_GRAPHS);
    const int gmax = clampi(batch[lastb], N_GRAPHS);
    const int gspan = gmax - gmin + 1;
    const bool use_lds = (gspan <= 64);

    for (int r4 = 0; r4 < 4; ++r4) {
        const int row0 = brow0 + r4 * 64;
        __syncthreads();   // Alds/ypart safe to overwrite (covers gred init on r4==0)
        {
            int row = t >> 2;
            int q4 = t & 3;
            int gr = row0 + row;
            us8* dst = (us8*)&Alds[row * 136 + q4 * 32];
            if (gr < N_NODES) {
                const us8* src = (q4 < 2)
                    ? (const us8*)(agg + (size_t)gr * 64 + (q4 & 1) * 32)
                    : (const us8*)(xb + (size_t)gr * 64 + (q4 & 1) * 32);
                dst[0] = src[0];
                dst[1] = src[1];
                dst[2] = src[2];
                dst[3] = src[3];
            } else {
                us8 z = {0, 0, 0, 0, 0, 0, 0, 0};
                dst[0] = z; dst[1] = z; dst[2] = z; dst[3] = z;
            }
        }
        __syncthreads();

        f32x4 acc[4][4] = {};
#pragma unroll
        for (int s = 0; s < 4; ++s) {
            s16x8 af[4];
#pragma unroll
            for (int mi = 0; mi < 4; mi++)
                af[mi] = *(const s16x8*)&Alds[(16 * mi + r16) * 136 + s * 32 + (quad << 3)];
#pragma unroll
            for (int mi = 0; mi < 4; mi++)
#pragma unroll
                for (int ni = 0; ni < 4; ni++)
                    acc[mi][ni] = __builtin_amdgcn_mfma_f32_16x16x32_bf16(
                        af[mi], bfr[s][ni], acc[mi][ni], 0, 0, 0);
        }

#pragma unroll
        for (int mi = 0; mi < 4; mi++) {
#pragma unroll
            for (int r = 0; r < 4; r++) {
                float p0 = 0.f, p1 = 0.f;
#pragma unroll
                for (int ni = 0; ni < 4; ni++) {
                    float h = acc[mi][ni][r] + blv[ni];
                    h = (h > 0.f) ? h : 0.01f * h;
                    p0 = fmaf(h, w0v[ni], p0);
                    p1 = fmaf(h, w1v[ni], p1);
                }
#pragma unroll
                for (int off = 1; off < 16; off <<= 1) {
                    p0 += __shfl_xor(p0, off, 16);
                    p1 += __shfl_xor(p1, off, 16);
                }
                if (r16 == 0) {
                    int rl = 16 * mi + (quad << 2) + r;
                    ypart[w][rl][0] = p0;
                    ypart[w][rl][1] = p1;
                }
            }
        }
        __syncthreads();

        if (t < 128) {
            int rl = t >> 1, cc = t & 1;
            int node = row0 + rl;
            if (node < N_NODES) {
                float s = ypart[0][rl][cc] + ypart[1][rl][cc]
                        + ypart[2][rl][cc] + ypart[3][rl][cc];
                int g = clampi(batch[node], N_GRAPHS);
                if (use_lds) atomicAdd(&gred[g - gmin][cc], s);
                else atomicAdd(&gacc[g * 2 + cc], s);
            }
        }
    }
    __syncthreads();
    if (use_lds && t < gspan * 2) {
        int gg = t >> 1, c2 = t & 1;
        float v = gred[gg][c2];
        if (v != 0.f) atomicAdd(&gacc[(gmin + gg) * 2 + c2], v);
    }
}

// K7: finalize (counts from boundary diffs)
__global__ void k_fin(const float* __restrict__ gacc, const int* __restrict__ bnd,
                      const float* __restrict__ bc, float* __restrict__ out) {
    int t = blockIdx.x * blockDim.x + threadIdx.x;
    if (t < N_GRAPHS * 2) {
        int g = t >> 1, c = t & 1;
        int cnt = bnd[g + 1] - bnd[g];
        out[t] = gacc[t] / (float)(cnt > 1 ? cnt : 1) + bc[c];
    }
}

extern "C" void kernel_launch(void* const* d_in, const int* in_sizes, int n_in,
                              void* d_out, int out_size, void* d_ws, size_t ws_size,
                              hipStream_t stream) {
    const float* x  = (const float*)d_in[0];
    const int* ei   = (const int*)d_in[1];
    const int* batch= (const int*)d_in[2];
    const float* Wl = (const float*)d_in[3];
    const float* bl = (const float*)d_in[4];
    const float* Wr = (const float*)d_in[5];
    const float* Wc = (const float*)d_in[6];
    const float* bc = (const float*)d_in[7];
    float* out = (float*)d_out;

    char* ws = (char*)d_ws;
    float* gacc        = (float*)(ws + OFF_GACC);
    int* base          = (int*)(ws + OFF_BASE);
    ushort_t* counts   = (ushort_t*)(ws + OFF_COUNTS);
    unsigned int* sd   = (unsigned int*)(ws + OFF_SD);
    int* srcs          = (int*)(ws + OFF_SRC);
    ushort_t* xb       = (ushort_t*)(ws + OFF_SRC);  // overlays srcs after gather
    unsigned char* x8  = (unsigned char*)(ws + OFF_X8);
    int* ep            = (int*)(ws + OFF_EP);
    ushort_t* agg      = (ushort_t*)(ws + OFF_EP);   // overlays dead ep
    ushort_t* WT       = (ushort_t*)(ws + OFF_WT);
    int* bnd           = (int*)(ws + OFF_BND);

    hipMemsetAsync(ws, 0, ZBYTES, stream);
    k_count      <<<NBLK, 256, 0, stream>>>(ei, counts);
    k_scan_col   <<<NB, 256, 0, stream>>>(counts, base);
    k_scan_bucket<<<1, 512, 0, stream>>>(base);
    k_scatter    <<<NBLK, 512, 0, stream>>>(ei, counts, base, ep);
    k_csr        <<<NB, 256, 0, stream>>>(ep, base, srcs, sd);
    k_prep       <<<PREP_CONV_BLOCKS + PREP_BW_BLOCKS + PREP_BND_BLOCKS, 256, 0, stream>>>(
                     x, x8, Wl, Wr, WT, batch, bnd);
    k_gather8    <<<(N_NODES + 3) / 4, 256, 0, stream>>>(x8, sd, srcs, agg);
    k_convb      <<<(N_NODES * 16 + 255) / 256, 256, 0, stream>>>(x, xb);
    k_gemm       <<<(N_NODES + 255) / 256, 256, 0, stream>>>(agg, xb, WT, bl, Wc, batch, gacc);
    k_fin        <<<4, 256, 0, stream>>>(gacc, bnd, bc, out);
}